// Round 3
// baseline (700.982 us; speedup 1.0000x reference)
//
#include <hip/hip_runtime.h>
#include <stdint.h>

#define SEQ   2048
#define DIM   64
#define BH    48
#define NELEM (BH*SEQ*DIM)          // 6291456

typedef __attribute__((ext_vector_type(4))) float f32x4;
typedef __attribute__((ext_vector_type(8))) short bf16x8;

#define MFMA_BF16 __builtin_amdgcn_mfma_f32_16x16x32_bf16

static __device__ __forceinline__ unsigned short f2bf(float x){
  unsigned int u = __float_as_uint(x);
  u += 0x7fffu + ((u >> 16) & 1u);
  return (unsigned short)(u >> 16);
}
static __device__ __forceinline__ float bf2f(unsigned int h){
  return __uint_as_float(h << 16);
}

// ---------------- prep: K -> (Khi, Klo) bf16 split ----------------
__global__ void prep_split_k(const float* __restrict__ K,
                             unsigned short* __restrict__ Khi,
                             unsigned short* __restrict__ Klo){
  const int n4 = NELEM/4;
  for (int i = blockIdx.x*blockDim.x + threadIdx.x; i < n4; i += gridDim.x*blockDim.x){
    float4 k = ((const float4*)K)[i];
    float kv[4] = {k.x,k.y,k.z,k.w};
    unsigned short h[4], lo[4];
    #pragma unroll
    for (int j=0;j<4;++j){
      h[j]  = f2bf(kv[j]);
      lo[j] = f2bf(kv[j] - bf2f(h[j]));
    }
    uint2 hp, lp;
    hp.x = (unsigned)h[0]  | ((unsigned)h[1]<<16);
    hp.y = (unsigned)h[2]  | ((unsigned)h[3]<<16);
    lp.x = (unsigned)lo[0] | ((unsigned)lo[1]<<16);
    lp.y = (unsigned)lo[2] | ((unsigned)lo[3]<<16);
    ((uint2*)Khi)[i] = hp;
    ((uint2*)Klo)[i] = lp;
  }
}

// ---------------- prep: V -> Vt bf16 transposed [bh][d][s] ----------------
__global__ void prep_transpose_v(const float* __restrict__ V,
                                 unsigned short* __restrict__ Vt){
  __shared__ float tile[64][65];
  int bh = blockIdx.x >> 5;          // 32 s-chunks of 64
  int s0 = (blockIdx.x & 31) << 6;
  int t  = threadIdx.x;              // 256 threads
  const float* Vb = V + ((size_t)bh*SEQ + s0)*DIM;
  #pragma unroll
  for (int r=0;r<4;++r){
    int f = r*1024 + t*4;
    int s = f >> 6, d = f & 63;
    float4 v = *(const float4*)(Vb + f);
    tile[s][d+0]=v.x; tile[s][d+1]=v.y; tile[s][d+2]=v.z; tile[s][d+3]=v.w;
  }
  __syncthreads();
  int d = t >> 2, si = (t & 3) << 4;
  unsigned int o[8];
  #pragma unroll
  for (int u=0;u<8;++u){
    unsigned short a = f2bf(tile[si+2*u  ][d]);
    unsigned short b = f2bf(tile[si+2*u+1][d]);
    o[u] = (unsigned)a | ((unsigned)b<<16);
  }
  unsigned short* orow = Vt + (size_t)bh*DIM*SEQ + (size_t)d*SEQ + s0 + si;
  uint4 p0 = make_uint4(o[0],o[1],o[2],o[3]);
  uint4 p1 = make_uint4(o[4],o[5],o[6],o[7]);
  ((uint4*)orow)[0] = p0;
  ((uint4*)orow)[1] = p1;
}

// Q fragment loaders (B-operand layout: col=q=l&15, k=d=(l>>4)*8+j, chunk ks -> d+32ks)
static __device__ __forceinline__ void load_q_hi(const float* Qrow, bf16x8* qh){
  #pragma unroll
  for (int ks=0; ks<2; ++ks){
    float4 a = *(const float4*)(Qrow + ks*32);
    float4 b = *(const float4*)(Qrow + ks*32 + 4);
    float x[8] = {a.x,a.y,a.z,a.w,b.x,b.y,b.z,b.w};
    #pragma unroll
    for (int j=0;j<8;++j) qh[ks][j] = (short)f2bf(x[j]*0.125f);
  }
}
static __device__ __forceinline__ void load_q_hilo(const float* Qrow, bf16x8* qh, bf16x8* ql){
  #pragma unroll
  for (int ks=0; ks<2; ++ks){
    float4 a = *(const float4*)(Qrow + ks*32);
    float4 b = *(const float4*)(Qrow + ks*32 + 4);
    float x[8] = {a.x,a.y,a.z,a.w,b.x,b.y,b.z,b.w};
    #pragma unroll
    for (int j=0;j<8;++j){
      float v = x[j]*0.125f;
      unsigned short h = f2bf(v);
      qh[ks][j] = (short)h;
      ql[ks][j] = (short)f2bf(v - bf2f(h));
    }
  }
}

// ---------------- pass 1: rowsums (hi-only scores), no LDS, no barriers ----------------
// swapped operands: S^T = K . Q^T ; D[col=q=l&15][row=kv=4*(l>>4)+r]
__global__ __launch_bounds__(256, 4) void pass1_rowsum(
    const float* __restrict__ Q,
    const unsigned short* __restrict__ Khi,
    float* __restrict__ rinv_g){
  int tid = threadIdx.x;
  int w = tid >> 6, l = tid & 63;
  int lr = l & 15, lg = l >> 4;

  int swz = (blockIdx.x & 7)*(768/8) + (blockIdx.x >> 3);   // bijective, 768%8==0
  int tA = swz*8 + w*2;            // wave handles q-tiles tA, tA+1 (same head)
  int bh = tA >> 7;
  int q0A = (tA & 127) << 4, q0B = q0A + 16;
  size_t bhq = (size_t)bh*SEQ;

  const float* QrowA = Q + (bhq + q0A + lr)*DIM + lg*8;
  bf16x8 qA[2], qB[2];
  load_q_hi(QrowA, qA);
  load_q_hi(QrowA + 16*DIM, qB);

  const unsigned short* Khb = Khi + bhq*DIM;
  float rsA = 0.f, rsB = 0.f;
  for (int t=0; t<128; ++t){
    const unsigned short* kr = Khb + (size_t)(t*16 + lr)*DIM + lg*8;
    bf16x8 kh0 = *(const bf16x8*)kr;
    bf16x8 kh1 = *(const bf16x8*)(kr + 32);
    f32x4 a = {0,0,0,0}, b = {0,0,0,0};
    a = MFMA_BF16(kh0, qA[0], a, 0,0,0);
    a = MFMA_BF16(kh1, qA[1], a, 0,0,0);
    b = MFMA_BF16(kh0, qB[0], b, 0,0,0);
    b = MFMA_BF16(kh1, qB[1], b, 0,0,0);
    #pragma unroll
    for (int r=0;r<4;++r){ rsA += __expf(a[r]); rsB += __expf(b[r]); }
  }
  // reduce across the 4 lane-groups (same q = l&15)
  rsA += __shfl_xor(rsA, 16, 64);  rsA += __shfl_xor(rsA, 32, 64);
  rsB += __shfl_xor(rsB, 16, 64);  rsB += __shfl_xor(rsB, 32, 64);
  if (l < 16){
    rinv_g[bhq + q0A + l] = 1.0f/(rsA + 1e-8f);
    rinv_g[bhq + q0B + l] = 1.0f/(rsB + 1e-8f);
  }
}

// ---------------- pass 2: exact scores, attn write from regs, PV ----------------
__global__ __launch_bounds__(256, 4) void pass2_main(
    const float* __restrict__ Q,
    const unsigned short* __restrict__ Khi,
    const unsigned short* __restrict__ Klo,
    const unsigned short* __restrict__ Vt,
    const float* __restrict__ rinv_g,
    float* __restrict__ ctx_out,
    float* __restrict__ attn_out){
  int tid = threadIdx.x;
  int w = tid >> 6, l = tid & 63;
  int lr = l & 15, lg = l >> 4;

  int swz = (blockIdx.x & 7)*(1536/8) + (blockIdx.x >> 3);  // bijective, 1536%8==0
  int tile = swz*4 + w;
  int bh = tile >> 7;
  int q0 = (tile & 127) << 4;
  size_t bhq = (size_t)bh*SEQ;

  bf16x8 qh[2], ql[2];
  load_q_hilo(Q + (bhq + q0 + lr)*DIM + lg*8, qh, ql);
  float rv = rinv_g[bhq + q0 + lr];

  const unsigned short* Khb = Khi + bhq*DIM;
  const unsigned short* Klb = Klo + bhq*DIM;
  const unsigned short* Vtb = Vt  + bhq*DIM;     // [d][s] for this head
  float* attn_row = attn_out + (bhq + q0 + lr)*SEQ;

  f32x4 o0={0,0,0,0}, o1={0,0,0,0}, o2={0,0,0,0}, o3={0,0,0,0};

  int src0 = lr + ((lg & 1) ? 32 : 0);
  int src1 = src0 + 16;
  bool losel = (lg < 2);

  for (int c=0; c<64; ++c){
    int kvc = c*32;
    // ---- QK^T for two 16-kv tiles (hi/lo split, 12 MFMA) ----
    const unsigned short* krA  = Khb + (size_t)(kvc + lr)*DIM + lg*8;
    const unsigned short* krlA = Klb + (size_t)(kvc + lr)*DIM + lg*8;
    bf16x8 kh0A = *(const bf16x8*)krA,        kh1A = *(const bf16x8*)(krA + 32);
    bf16x8 kl0A = *(const bf16x8*)krlA,       kl1A = *(const bf16x8*)(krlA + 32);
    bf16x8 kh0B = *(const bf16x8*)(krA  + 16*DIM), kh1B = *(const bf16x8*)(krA  + 16*DIM + 32);
    bf16x8 kl0B = *(const bf16x8*)(krlA + 16*DIM), kl1B = *(const bf16x8*)(krlA + 16*DIM + 32);

    f32x4 aA={0,0,0,0}, bA={0,0,0,0}, aB={0,0,0,0}, bB={0,0,0,0};
    aA = MFMA_BF16(kh0A, qh[0], aA, 0,0,0);
    aA = MFMA_BF16(kh1A, qh[1], aA, 0,0,0);
    bA = MFMA_BF16(kl0A, qh[0], bA, 0,0,0);
    bA = MFMA_BF16(kl1A, qh[1], bA, 0,0,0);
    bA = MFMA_BF16(kh0A, ql[0], bA, 0,0,0);
    bA = MFMA_BF16(kh1A, ql[1], bA, 0,0,0);
    aB = MFMA_BF16(kh0B, qh[0], aB, 0,0,0);
    aB = MFMA_BF16(kh1B, qh[1], aB, 0,0,0);
    bB = MFMA_BF16(kl0B, qh[0], bB, 0,0,0);
    bB = MFMA_BF16(kl1B, qh[1], bB, 0,0,0);
    bB = MFMA_BF16(kh0B, ql[0], bB, 0,0,0);
    bB = MFMA_BF16(kh1B, ql[1], bB, 0,0,0);

    // ---- exp + normalize; lane holds 4 consecutive kv of row q=lr ----
    float pA[4], pB[4];
    #pragma unroll
    for (int r=0;r<4;++r){
      pA[r] = __expf(aA[r] + bA[r]) * rv;
      pB[r] = __expf(aB[r] + bB[r]) * rv;
    }
    // attn store: row q0+lr, cols kvc+4lg.. (aligned float4, 64B segments/row)
    float4 stA = {pA[0], pA[1], pA[2], pA[3]};
    float4 stB = {pB[0], pB[1], pB[2], pB[3]};
    *(float4*)(attn_row + kvc + 4*lg)      = stA;
    *(float4*)(attn_row + kvc + 16 + 4*lg) = stB;

    // ---- pack to bf16 and redistribute to MFMA-A layout (k=kv=8*lg+j) ----
    unsigned a0 = (unsigned)f2bf(pA[0]) | ((unsigned)f2bf(pA[1])<<16);
    unsigned a1 = (unsigned)f2bf(pA[2]) | ((unsigned)f2bf(pA[3])<<16);
    unsigned b0 = (unsigned)f2bf(pB[0]) | ((unsigned)f2bf(pB[1])<<16);
    unsigned b1 = (unsigned)f2bf(pB[2]) | ((unsigned)f2bf(pB[3])<<16);
    unsigned t0a = (unsigned)__shfl((int)a0, src0, 64);
    unsigned t1a = (unsigned)__shfl((int)a1, src0, 64);
    unsigned t2a = (unsigned)__shfl((int)a0, src1, 64);
    unsigned t3a = (unsigned)__shfl((int)a1, src1, 64);
    unsigned t0b = (unsigned)__shfl((int)b0, src0, 64);
    unsigned t1b = (unsigned)__shfl((int)b1, src0, 64);
    unsigned t2b = (unsigned)__shfl((int)b0, src1, 64);
    unsigned t3b = (unsigned)__shfl((int)b1, src1, 64);
    union { bf16x8 v; unsigned u[4]; } pu;
    pu.u[0] = losel ? t0a : t0b;
    pu.u[1] = losel ? t1a : t1b;
    pu.u[2] = losel ? t2a : t2b;
    pu.u[3] = losel ? t3a : t3b;
    bf16x8 pa = pu.v;

    // ---- PV: 4 d-tiles, B = Vt[d][kv] 16B loads ----
    bf16x8 vb0 = *(const bf16x8*)(Vtb + (size_t)( 0 + lr)*SEQ + kvc + lg*8);
    bf16x8 vb1 = *(const bf16x8*)(Vtb + (size_t)(16 + lr)*SEQ + kvc + lg*8);
    bf16x8 vb2 = *(const bf16x8*)(Vtb + (size_t)(32 + lr)*SEQ + kvc + lg*8);
    bf16x8 vb3 = *(const bf16x8*)(Vtb + (size_t)(48 + lr)*SEQ + kvc + lg*8);
    o0 = MFMA_BF16(pa, vb0, o0, 0,0,0);
    o1 = MFMA_BF16(pa, vb1, o1, 0,0,0);
    o2 = MFMA_BF16(pa, vb2, o2, 0,0,0);
    o3 = MFMA_BF16(pa, vb3, o3, 0,0,0);
  }

  // ---- ctx epilogue: D[row=q=4lg+r][col=d=n*16+lr] (already normalized) ----
  #pragma unroll
  for (int r=0;r<4;++r){
    size_t rowoff = (bhq + q0 + lg*4 + r)*DIM + lr;
    ctx_out[rowoff +  0] = o0[r];
    ctx_out[rowoff + 16] = o1[r];
    ctx_out[rowoff + 32] = o2[r];
    ctx_out[rowoff + 48] = o3[r];
  }
}

extern "C" void kernel_launch(void* const* d_in, const int* in_sizes, int n_in,
                              void* d_out, int out_size, void* d_ws, size_t ws_size,
                              hipStream_t stream) {
  const float* Q = (const float*)d_in[0];
  const float* K = (const float*)d_in[1];
  const float* V = (const float*)d_in[2];
  float* ctx_out  = (float*)d_out;
  float* attn_out = ctx_out + (size_t)NELEM;

  unsigned short* Khi = (unsigned short*)d_ws;
  unsigned short* Klo = Khi + (size_t)NELEM;
  unsigned short* Vt  = Klo + (size_t)NELEM;
  float* rinv_g = (float*)(Vt + (size_t)NELEM);

  prep_split_k<<<1024, 256, 0, stream>>>(K, Khi, Klo);
  prep_transpose_v<<<BH*32, 256, 0, stream>>>(V, Vt);
  pass1_rowsum<<<768, 256, 0, stream>>>(Q, Khi, rinv_g);
  pass2_main<<<1536, 256, 0, stream>>>(Q, Khi, Klo, Vt, rinv_g, ctx_out, attn_out);
}